// Round 8
// baseline (108.957 us; speedup 1.0000x reference)
//
#include <hip/hip_runtime.h>
#include <math.h>

#define QSCALE (0.2886751345948129f * 1.4426950408889634f)  // 1/sqrt(12) * log2(e)

#if __has_builtin(__builtin_amdgcn_exp2f)
#define EXP2F(x) __builtin_amdgcn_exp2f(x)
#else
#define EXP2F(x) exp2f(x)
#endif

typedef __attribute__((ext_vector_type(8))) _Float16 half8;
typedef __attribute__((ext_vector_type(4))) _Float16 half4_t;
typedef __attribute__((ext_vector_type(4))) float floatx4;
typedef __attribute__((ext_vector_type(2))) unsigned int uint2v;

#define MFMA32F16(a, b, c) __builtin_amdgcn_mfma_f32_16x16x32_f16((a), (b), (c), 0, 0, 0)
#define MFMA16F16(a, b, c) __builtin_amdgcn_mfma_f32_16x16x16f16((a), (b), (c), 0, 0, 0)

static __device__ inline float bperm(float v, int addr_bytes) {
    return __int_as_float(__builtin_amdgcn_ds_bpermute(addr_bytes, __float_as_int(v)));
}

// Butterfly max over lane^16 / lane^32. Preferred: gfx950 permlane swap
// intrinsics (VALU pipe, no LDS round-trip). The intrinsic returns BOTH
// post-swap registers ({vdst,vsrc}); feeding v to both inputs makes
// fmax(r0,r1) == fmax(v, v[lane^16]) in every lane (direction-independent
// because fmax is commutative). NOTE: must NOT be done via inline asm with
// two copies of v -- regalloc may alias them into one register (Round-6 bug).
static __device__ inline float xmax16(float v) {
#if __has_builtin(__builtin_amdgcn_permlane16_swap)
    unsigned int u = __float_as_uint(v);
    uint2v r = __builtin_amdgcn_permlane16_swap(u, u, false, false);
    return fmaxf(__uint_as_float(r[0]), __uint_as_float(r[1]));
#else
    return fmaxf(v, bperm(v, ((int)(threadIdx.x & 63) ^ 16) << 2));
#endif
}
static __device__ inline float xmax32(float v) {
#if __has_builtin(__builtin_amdgcn_permlane32_swap)
    unsigned int u = __float_as_uint(v);
    uint2v r = __builtin_amdgcn_permlane32_swap(u, u, false, false);
    return fmaxf(__uint_as_float(r[0]), __uint_as_float(r[1]));
#else
    return fmaxf(v, bperm(v, ((int)(threadIdx.x & 63) ^ 32) << 2));
#endif
}

// ---------------- Kernel P: prep (wswz | mask_scan) ------------------------
// blocks 0..17: weight swizzle -> fp16 hi/lo B-frags
// blocks 18..25: per-batch mask scan/compaction
// NO zero pass: qkv epilogue writes its own pads; attn masks the last tile.
__global__ __launch_bounds__(256)
void prep(const float* __restrict__ Wq, const float* __restrict__ Wk,
          const float* __restrict__ Wv, const int* __restrict__ mask,
          _Float16* __restrict__ wfh, _Float16* __restrict__ wfl,
          int* __restrict__ dst, int* __restrict__ nvalid)
{
    const int b = blockIdx.x;
    const int tid = threadIdx.x;
    if (b < 18) {
        int t = b * 256 + tid;
        if (t >= 4608) return;             // 24 ks * 3 nt * 64 lanes
        int lane = t & 63;
        int nt   = (t >> 6) % 3;
        int ks   = t / 192;
        const float* W = (nt == 0) ? Wq : (nt == 1) ? Wk : Wv;
        const float scale = (nt == 0) ? QSCALE : 1.0f;
        int col = lane & 15;
        int q8  = lane >> 4;
        half8 hi, lo;
        #pragma unroll
        for (int j = 0; j < 8; ++j) {
            int dim = ks * 32 + q8 * 8 + j;
            float f = (col < 12) ? W[dim * 12 + col] * scale : 0.0f;
            _Float16 h = (_Float16)f;
            hi[j] = h;
            lo[j] = (_Float16)(f - (float)h);
        }
        size_t off = ((size_t)(ks * 3 + nt) * 64 + lane) * 8;
        *(half8*)(wfh + off) = hi;
        *(half8*)(wfl + off) = lo;
    } else {
        __shared__ int cnt[256];
        const int bb = b - 18;
        const int* mb = mask + bb * 2048;
        int local[8]; int c = 0;
        #pragma unroll
        for (int i = 0; i < 8; ++i) { local[i] = (mb[tid * 8 + i] != 0); c += local[i]; }
        cnt[tid] = c;
        __syncthreads();
        for (int off = 1; off < 256; off <<= 1) {
            int u = cnt[tid];
            int add = (tid >= off) ? cnt[tid - off] : 0;
            __syncthreads();
            cnt[tid] = u + add;
            __syncthreads();
        }
        int run = (tid == 0) ? 0 : cnt[tid - 1];
        int* db = dst + bb * 2048;
        #pragma unroll
        for (int i = 0; i < 8; ++i) { db[tid * 8 + i] = local[i] ? run : -1; run += local[i]; }
        if (tid == 255) nvalid[bb] = cnt[255];
    }
}

// ---------------- Kernel 1: QKV projection, fp16-split MFMA ----------------
// grid=1024 (16 rows/block), block=256 (4 waves split K: 6 x 32-dim steps).
// Epilogue packs attention operands AND writes the zero pads:
//   Q -> qA (q_hi dup in K-slots 0..11 & 16..27) + qB (q_lo in 0..11, zeros
//        at 16..27)
//   K -> kfp packed A-frag: k_hi slots 0..11, k_lo slots 16..27, zeros at
//        12..15 & 28..31 (written by the col 12..15 threads)
//   V^T -> vtf A-frag (fp16) + ones row (l-accumulator)
__global__ __launch_bounds__(256, 3)
void qkv_mfma(const float* __restrict__ x, const _Float16* __restrict__ wfh,
              const _Float16* __restrict__ wfl, const int* __restrict__ dst,
              _Float16* __restrict__ qA, _Float16* __restrict__ qB,
              _Float16* __restrict__ kfp, _Float16* __restrict__ vtf)
{
    __shared__ __align__(16) float cbuf[3072];   // [w][nt][lane][4]
    const int tid  = threadIdx.x;
    const int lane = tid & 63;
    const int w    = tid >> 6;
    const int g    = blockIdx.x;
    const int rowbase = g * 16;
    const int m15 = lane & 15;
    const int q8  = lane >> 4;

    const float* xbase = x + (size_t)(rowbase + m15) * 768 + q8 * 8;
    const half8* WH = (const half8*)wfh;
    const half8* WL = (const half8*)wfl;

    // issue ALL x loads up front (independent, 12 in flight)
    float xv[6][8];
    #pragma unroll
    for (int s = 0; s < 6; ++s) {
        const int ks = w * 6 + s;
        *(float4*)(xv[s])     = *(const float4*)(xbase + ks * 32);
        *(float4*)(xv[s] + 4) = *(const float4*)(xbase + ks * 32 + 4);
    }

    floatx4 acc0 = {0.f, 0.f, 0.f, 0.f};
    floatx4 acc1 = acc0, acc2 = acc0;

    // weight frags: double-buffered
    half8 bh[2][3], bl[2][3];
    {
        const int ks = w * 6;
        #pragma unroll
        for (int n = 0; n < 3; ++n) {
            bh[0][n] = WH[(ks * 3 + n) * 64 + lane];
            bl[0][n] = WL[(ks * 3 + n) * 64 + lane];
        }
    }

    #pragma unroll
    for (int s = 0; s < 6; ++s) {
        const int cur = s & 1, nxt = cur ^ 1;
        if (s < 5) {
            const int ksn = w * 6 + s + 1;
            #pragma unroll
            for (int n = 0; n < 3; ++n) {
                bh[nxt][n] = WH[(ksn * 3 + n) * 64 + lane];
                bl[nxt][n] = WL[(ksn * 3 + n) * 64 + lane];
            }
        }
        half8 ah, al;
        #pragma unroll
        for (int j = 0; j < 8; ++j) {
            _Float16 h = (_Float16)xv[s][j];
            ah[j] = h;
            al[j] = (_Float16)(xv[s][j] - (float)h);
        }
        acc0 = MFMA32F16(ah, bh[cur][0], acc0);
        acc1 = MFMA32F16(ah, bh[cur][1], acc1);
        acc2 = MFMA32F16(ah, bh[cur][2], acc2);
        acc0 = MFMA32F16(al, bh[cur][0], acc0);
        acc1 = MFMA32F16(al, bh[cur][1], acc1);
        acc2 = MFMA32F16(al, bh[cur][2], acc2);
        acc0 = MFMA32F16(ah, bl[cur][0], acc0);
        acc1 = MFMA32F16(ah, bl[cur][1], acc1);
        acc2 = MFMA32F16(ah, bl[cur][2], acc2);
    }

    *(floatx4*)(cbuf + ((w * 3 + 0) * 64 + lane) * 4) = acc0;
    *(floatx4*)(cbuf + ((w * 3 + 1) * 64 + lane) * 4) = acc1;
    *(floatx4*)(cbuf + ((w * 3 + 2) * 64 + lane) * 4) = acc2;
    __syncthreads();
    if (w < 3) {
        floatx4 t0 = *(const floatx4*)(cbuf + ((0 * 3 + w) * 64 + lane) * 4);
        floatx4 t1 = *(const floatx4*)(cbuf + ((1 * 3 + w) * 64 + lane) * 4);
        floatx4 t2 = *(const floatx4*)(cbuf + ((2 * 3 + w) * 64 + lane) * 4);
        floatx4 t3 = *(const floatx4*)(cbuf + ((3 * 3 + w) * 64 + lane) * 4);
        floatx4 tot = t0 + t1 + t2 + t3;
        const int col = m15;
        const int r0  = q8 * 4;
        #pragma unroll
        for (int r = 0; r < 4; ++r) {
            const int row = rowbase + r0 + r;
            const float val = tot[r];
            if (w == 0) {                  // Q -> qA (hi dup) + qB (lo + zero pad)
                if (col < 12) {
                    size_t fb = (size_t)g * 64;
                    size_t offL = (fb + (col >> 3) * 16 + (r0 + r)) * 8 + (col & 7);
                    size_t offH = (fb + (2 + (col >> 3)) * 16 + (r0 + r)) * 8 + (col & 7);
                    _Float16 h = (_Float16)val;
                    qA[offL] = h;
                    qA[offH] = h;          // duplicate hi into K-slots 16..27
                    qB[offL] = (_Float16)(val - (float)h);
                    qB[offH] = (_Float16)0.0f;   // zero K-slots 16..27
                }
            } else {
                const int d = dst[row];
                if (d >= 0) {
                    const int bb = row >> 11;
                    if (w == 1) {          // K -> packed hi|lo A-frag (compacted)
                        size_t fb = ((size_t)(bb * 128 + (d >> 4))) * 64;
                        size_t offH = (fb + (col >> 3) * 16 + (d & 15)) * 8 + (col & 7);
                        size_t offL = (fb + (2 + (col >> 3)) * 16 + (d & 15)) * 8 + (col & 7);
                        if (col < 12) {
                            _Float16 h = (_Float16)val;
                            kfp[offH] = h;
                            kfp[offL] = (_Float16)(val - (float)h);
                        } else {           // col 12..15: zero pads at slots 12..15 / 28..31
                            kfp[offH] = (_Float16)0.0f;
                            kfp[offL] = (_Float16)0.0f;
                        }
                    } else {               // V^T -> A-frag layout (fp16), + ones row
                        if (col < 12) {
                            size_t off = (((size_t)(bb * 128 + (d >> 4))) * 64
                                          + ((d & 15) >> 2) * 16 + col) * 4 + (d & 3);
                            vtf[off] = (_Float16)val;
                        } else if (col == 12) {   // l-accumulator ones row
                            size_t off = (((size_t)(bb * 128 + (d >> 4))) * 64
                                          + ((d & 15) >> 2) * 16 + 12) * 4 + (d & 3);
                            vtf[off] = (_Float16)1.0f;
                        }
                    }
                }
            }
        }
    }
}

// ---------------- Kernel 2: MFMA flash attention ---------------------------
// grid=1024 (ONE 16-row q-group per block), block=256 (4 waves stride-4 over
// 16-key tiles). XCD swizzle: batch = blockIdx&7 pins each batch's blocks to
// one XCD. Packed-K trick: k_hi slots 0..11, k_lo slots 16..27 of one
// A-frag; two MFMAs give all three fp16-split terms. Cross-lane softmax max
// via permlane-swap intrinsics (VALU) when available, else ds_bpermute --
// same fmax tree over the same values, bit-identical result. Last-tile
// invalid keys zeroed in-register.
__global__ __launch_bounds__(256)
void attn(const _Float16* __restrict__ qAf, const _Float16* __restrict__ qBf,
          const _Float16* __restrict__ kfp, const _Float16* __restrict__ vtf,
          const int* __restrict__ nvalid, float* __restrict__ out)
{
    __shared__ float cm[256];
    __shared__ __align__(16) floatx4 co[256];
    const int tid  = threadIdx.x;
    const int lane = tid & 63;
    const int w    = tid >> 6;
    const int bb   = blockIdx.x & 7;       // XCD-pinned batch
    const int gl   = blockIdx.x >> 3;      // 0..127 within batch
    const int g0   = bb * 128 + gl;        // q-group
    const int m15  = lane & 15;

    const half8 qA0 = *(const half8*)(qAf + ((size_t)g0 * 64 + lane) * 8);
    const half8 qB0 = *(const half8*)(qBf + ((size_t)g0 * 64 + lane) * 8);

    const half8* KP = (const half8*)kfp + (size_t)bb * 128 * 64;
    const half4_t* VT = (const half4_t*)vtf + (size_t)bb * 128 * 64;

    const int nv = nvalid[bb];
    const int nt = (nv + 15) >> 4;         // 16-key tiles (<=128)

    float m0 = -INFINITY;
    floatx4 o0 = {0.f, 0.f, 0.f, 0.f};

    int t = w;
    half8 kp;
    half4_t va;
    if (t < nt) {
        kp = KP[t * 64 + lane];
        va = VT[t * 64 + lane];
    }
    for (; t < nt; t += 4) {
        half8 nkp; half4_t nva;
        if (t + 4 < nt) {
            nkp = KP[(t + 4) * 64 + lane];
            nva = VT[(t + 4) * 64 + lane];
        }
        if (t == nt - 1) {                 // mask invalid keys of the last tile
            const int kb = t * 16;
            if (kb + m15 >= nv) {          // kp key index = t*16 + (lane&15)
                #pragma unroll
                for (int j = 0; j < 8; ++j) kp[j] = (_Float16)0.0f;
            }
            const int kv = kb + (lane >> 4) * 4;  // va key index = kv + j
            #pragma unroll
            for (int j = 0; j < 4; ++j)
                if (kv + j >= nv) va[j] = (_Float16)0.0f;
        }
        const floatx4 z = {0.f, 0.f, 0.f, 0.f};
        floatx4 s0a = MFMA32F16(kp, qA0, z);   // kh*qh + kl*qh
        floatx4 s0b = MFMA32F16(kp, qB0, z);   // kh*ql
        floatx4 s0 = s0a + s0b;
        {
            float pm = fmaxf(fmaxf(s0.x, s0.y), fmaxf(s0.z, s0.w));
            pm = xmax16(pm);
            pm = xmax32(pm);
            half4_t pb;
            if (__all(pm <= m0)) {             // defer: mnew == m0 exactly
                pb[0] = (_Float16)EXP2F(s0.x - m0);
                pb[1] = (_Float16)EXP2F(s0.y - m0);
                pb[2] = (_Float16)EXP2F(s0.z - m0);
                pb[3] = (_Float16)EXP2F(s0.w - m0);
            } else {
                float mnew = fmaxf(m0, pm);
                float corr = EXP2F(m0 - mnew);
                o0.x *= corr; o0.y *= corr; o0.z *= corr; o0.w *= corr;
                pb[0] = (_Float16)EXP2F(s0.x - mnew);
                pb[1] = (_Float16)EXP2F(s0.y - mnew);
                pb[2] = (_Float16)EXP2F(s0.z - mnew);
                pb[3] = (_Float16)EXP2F(s0.w - mnew);
                m0 = mnew;
            }
            o0 = MFMA16F16(va, pb, o0);
        }
        kp = nkp; va = nva;
    }

    // ---- 4-way combine ----
    cm[w * 64 + lane] = m0;
    co[w * 64 + lane] = o0;
    __syncthreads();
    if (w == 0) {
        float gm = -INFINITY;
        #pragma unroll
        for (int w2 = 0; w2 < 4; ++w2) gm = fmaxf(gm, cm[w2 * 64 + lane]);
        floatx4 O = {0.f, 0.f, 0.f, 0.f};
        #pragma unroll
        for (int w2 = 0; w2 < 4; ++w2) {
            float f = EXP2F(cm[w2 * 64 + lane] - gm);
            floatx4 ow = co[w2 * 64 + lane];
            O.x += ow.x * f; O.y += ow.y * f; O.z += ow.z * f; O.w += ow.w * f;
        }
        float L = bperm(O.x, (48 + m15) << 2);   // l at C row 12
        float inv = 1.0f / L;
        if ((lane >> 4) < 3) {
            float4 ov = make_float4(O.x * inv, O.y * inv, O.z * inv, O.w * inv);
            *(float4*)(out + ((size_t)g0 * 16 + m15) * 12 + (lane >> 4) * 4) = ov;
        }
    }
}

extern "C" void kernel_launch(void* const* d_in, const int* in_sizes, int n_in,
                              void* d_out, int out_size, void* d_ws, size_t ws_size,
                              hipStream_t stream) {
    const float* x    = (const float*)d_in[0];
    const int*   mask = (const int*)  d_in[1];
    const float* Wk   = (const float*)d_in[2];   // key_weight
    const float* Wq   = (const float*)d_in[3];   // query_weight
    const float* Wv   = (const float*)d_in[4];   // value_weight
    float* out = (float*)d_out;

    char* base = (char*)d_ws;
    _Float16* qA  = (_Float16*)(base);                    // 1 MB (poison ok)
    _Float16* qB  = (_Float16*)(base + (1u << 20));       // 1 MB (pads written by qkv)
    _Float16* kfp = (_Float16*)(base + (2u << 20));       // 1 MB (pads written by qkv)
    _Float16* vtf = (_Float16*)(base + (3u << 20));       // 0.5 MB (poison rows unread)
    _Float16* wfh = (_Float16*)(base + 3670016);          // 73728 B
    _Float16* wfl = (_Float16*)(base + 3670016 + 73728);  // 73728 B
    int* dst      = (int*)(base + 3817472);               // 64 KB
    int* nvalid   = (int*)(base + 3817472 + 65536);       // 32 B

    prep<<<26, 256, 0, stream>>>(Wq, Wk, Wv, mask, wfh, wfl, dst, nvalid);
    qkv_mfma<<<1024, 256, 0, stream>>>(x, wfh, wfl, dst, qA, qB, kfp, vtf);
    attn<<<1024, 256, 0, stream>>>(qA, qB, kfp, vtf, nvalid, out);
}

// Round 9
// 108.058 us; speedup vs baseline: 1.0083x; 1.0083x over previous
//
#include <hip/hip_runtime.h>
#include <math.h>

#define QSCALE (0.2886751345948129f * 1.4426950408889634f)  // 1/sqrt(12) * log2(e)

#if __has_builtin(__builtin_amdgcn_exp2f)
#define EXP2F(x) __builtin_amdgcn_exp2f(x)
#else
#define EXP2F(x) exp2f(x)
#endif

typedef __attribute__((ext_vector_type(8))) _Float16 half8;
typedef __attribute__((ext_vector_type(4))) _Float16 half4_t;
typedef __attribute__((ext_vector_type(4))) float floatx4;
typedef __attribute__((ext_vector_type(2))) unsigned int uint2v;

#define MFMA32F16(a, b, c) __builtin_amdgcn_mfma_f32_16x16x32_f16((a), (b), (c), 0, 0, 0)
#define MFMA16F16(a, b, c) __builtin_amdgcn_mfma_f32_16x16x16f16((a), (b), (c), 0, 0, 0)

static __device__ inline float bperm(float v, int addr_bytes) {
    return __int_as_float(__builtin_amdgcn_ds_bpermute(addr_bytes, __float_as_int(v)));
}

// Butterfly max over lane^16 / lane^32 via gfx950 permlane swap intrinsics
// (VALU pipe). The intrinsic returns BOTH post-swap registers; feeding v to
// both inputs makes fmax(r0,r1) == fmax(v, v[lane^16]) in every lane.
// (Inline-asm with two copies of v is WRONG: regalloc may alias them.)
static __device__ inline float xmax16(float v) {
#if __has_builtin(__builtin_amdgcn_permlane16_swap)
    unsigned int u = __float_as_uint(v);
    uint2v r = __builtin_amdgcn_permlane16_swap(u, u, false, false);
    return fmaxf(__uint_as_float(r[0]), __uint_as_float(r[1]));
#else
    return fmaxf(v, bperm(v, ((int)(threadIdx.x & 63) ^ 16) << 2));
#endif
}
static __device__ inline float xmax32(float v) {
#if __has_builtin(__builtin_amdgcn_permlane32_swap)
    unsigned int u = __float_as_uint(v);
    uint2v r = __builtin_amdgcn_permlane32_swap(u, u, false, false);
    return fmaxf(__uint_as_float(r[0]), __uint_as_float(r[1]));
#else
    return fmaxf(v, bperm(v, ((int)(threadIdx.x & 63) ^ 32) << 2));
#endif
}

// ---------------- Kernel P: prep (wswz | mask_scan) ------------------------
// blocks 0..17: weight swizzle -> fp16 hi/lo B-frags
// blocks 18..25: per-batch mask scan/compaction
// NO zero pass: qkv epilogue writes its own pads; attn masks the last tile.
__global__ __launch_bounds__(256)
void prep(const float* __restrict__ Wq, const float* __restrict__ Wk,
          const float* __restrict__ Wv, const int* __restrict__ mask,
          _Float16* __restrict__ wfh, _Float16* __restrict__ wfl,
          int* __restrict__ dst, int* __restrict__ nvalid)
{
    const int b = blockIdx.x;
    const int tid = threadIdx.x;
    if (b < 18) {
        int t = b * 256 + tid;
        if (t >= 4608) return;             // 24 ks * 3 nt * 64 lanes
        int lane = t & 63;
        int nt   = (t >> 6) % 3;
        int ks   = t / 192;
        const float* W = (nt == 0) ? Wq : (nt == 1) ? Wk : Wv;
        const float scale = (nt == 0) ? QSCALE : 1.0f;
        int col = lane & 15;
        int q8  = lane >> 4;
        half8 hi, lo;
        #pragma unroll
        for (int j = 0; j < 8; ++j) {
            int dim = ks * 32 + q8 * 8 + j;
            float f = (col < 12) ? W[dim * 12 + col] * scale : 0.0f;
            _Float16 h = (_Float16)f;
            hi[j] = h;
            lo[j] = (_Float16)(f - (float)h);
        }
        size_t off = ((size_t)(ks * 3 + nt) * 64 + lane) * 8;
        *(half8*)(wfh + off) = hi;
        *(half8*)(wfl + off) = lo;
    } else {
        __shared__ int cnt[256];
        const int bb = b - 18;
        const int* mb = mask + bb * 2048;
        int local[8]; int c = 0;
        #pragma unroll
        for (int i = 0; i < 8; ++i) { local[i] = (mb[tid * 8 + i] != 0); c += local[i]; }
        cnt[tid] = c;
        __syncthreads();
        for (int off = 1; off < 256; off <<= 1) {
            int u = cnt[tid];
            int add = (tid >= off) ? cnt[tid - off] : 0;
            __syncthreads();
            cnt[tid] = u + add;
            __syncthreads();
        }
        int run = (tid == 0) ? 0 : cnt[tid - 1];
        int* db = dst + bb * 2048;
        #pragma unroll
        for (int i = 0; i < 8; ++i) { db[tid * 8 + i] = local[i] ? run : -1; run += local[i]; }
        if (tid == 255) nvalid[bb] = cnt[255];
    }
}

// ---------------- Kernel 1: QKV projection, fp16-split MFMA ----------------
// grid=1024 (16 rows/block), block=256 (4 waves split K: 6 x 32-dim steps).
// Epilogue packs attention operands AND writes the zero pads:
//   Q -> qA (q_hi dup in K-slots 0..11 & 16..27) + qB (q_lo in 0..11, zeros
//        at 16..27)
//   K -> kfp packed A-frag: k_hi slots 0..11, k_lo slots 16..27, zeros at
//        12..15 & 28..31 (written by the col 12..15 threads)
//   V^T -> vtf A-frag (fp16) + ones row (l-accumulator)
__global__ __launch_bounds__(256, 3)
void qkv_mfma(const float* __restrict__ x, const _Float16* __restrict__ wfh,
              const _Float16* __restrict__ wfl, const int* __restrict__ dst,
              _Float16* __restrict__ qA, _Float16* __restrict__ qB,
              _Float16* __restrict__ kfp, _Float16* __restrict__ vtf)
{
    __shared__ __align__(16) float cbuf[3072];   // [w][nt][lane][4]
    const int tid  = threadIdx.x;
    const int lane = tid & 63;
    const int w    = tid >> 6;
    const int g    = blockIdx.x;
    const int rowbase = g * 16;
    const int m15 = lane & 15;
    const int q8  = lane >> 4;

    const float* xbase = x + (size_t)(rowbase + m15) * 768 + q8 * 8;
    const half8* WH = (const half8*)wfh;
    const half8* WL = (const half8*)wfl;

    // issue ALL x loads up front (independent, 12 in flight)
    float xv[6][8];
    #pragma unroll
    for (int s = 0; s < 6; ++s) {
        const int ks = w * 6 + s;
        *(float4*)(xv[s])     = *(const float4*)(xbase + ks * 32);
        *(float4*)(xv[s] + 4) = *(const float4*)(xbase + ks * 32 + 4);
    }

    floatx4 acc0 = {0.f, 0.f, 0.f, 0.f};
    floatx4 acc1 = acc0, acc2 = acc0;

    // weight frags: double-buffered
    half8 bh[2][3], bl[2][3];
    {
        const int ks = w * 6;
        #pragma unroll
        for (int n = 0; n < 3; ++n) {
            bh[0][n] = WH[(ks * 3 + n) * 64 + lane];
            bl[0][n] = WL[(ks * 3 + n) * 64 + lane];
        }
    }

    #pragma unroll
    for (int s = 0; s < 6; ++s) {
        const int cur = s & 1, nxt = cur ^ 1;
        if (s < 5) {
            const int ksn = w * 6 + s + 1;
            #pragma unroll
            for (int n = 0; n < 3; ++n) {
                bh[nxt][n] = WH[(ksn * 3 + n) * 64 + lane];
                bl[nxt][n] = WL[(ksn * 3 + n) * 64 + lane];
            }
        }
        half8 ah, al;
        #pragma unroll
        for (int j = 0; j < 8; ++j) {
            _Float16 h = (_Float16)xv[s][j];
            ah[j] = h;
            al[j] = (_Float16)(xv[s][j] - (float)h);
        }
        acc0 = MFMA32F16(ah, bh[cur][0], acc0);
        acc1 = MFMA32F16(ah, bh[cur][1], acc1);
        acc2 = MFMA32F16(ah, bh[cur][2], acc2);
        acc0 = MFMA32F16(al, bh[cur][0], acc0);
        acc1 = MFMA32F16(al, bh[cur][1], acc1);
        acc2 = MFMA32F16(al, bh[cur][2], acc2);
        acc0 = MFMA32F16(ah, bl[cur][0], acc0);
        acc1 = MFMA32F16(ah, bl[cur][1], acc1);
        acc2 = MFMA32F16(ah, bl[cur][2], acc2);
    }

    *(floatx4*)(cbuf + ((w * 3 + 0) * 64 + lane) * 4) = acc0;
    *(floatx4*)(cbuf + ((w * 3 + 1) * 64 + lane) * 4) = acc1;
    *(floatx4*)(cbuf + ((w * 3 + 2) * 64 + lane) * 4) = acc2;
    __syncthreads();
    if (w < 3) {
        floatx4 t0 = *(const floatx4*)(cbuf + ((0 * 3 + w) * 64 + lane) * 4);
        floatx4 t1 = *(const floatx4*)(cbuf + ((1 * 3 + w) * 64 + lane) * 4);
        floatx4 t2 = *(const floatx4*)(cbuf + ((2 * 3 + w) * 64 + lane) * 4);
        floatx4 t3 = *(const floatx4*)(cbuf + ((3 * 3 + w) * 64 + lane) * 4);
        floatx4 tot = t0 + t1 + t2 + t3;
        const int col = m15;
        const int r0  = q8 * 4;
        #pragma unroll
        for (int r = 0; r < 4; ++r) {
            const int row = rowbase + r0 + r;
            const float val = tot[r];
            if (w == 0) {                  // Q -> qA (hi dup) + qB (lo + zero pad)
                if (col < 12) {
                    size_t fb = (size_t)g * 64;
                    size_t offL = (fb + (col >> 3) * 16 + (r0 + r)) * 8 + (col & 7);
                    size_t offH = (fb + (2 + (col >> 3)) * 16 + (r0 + r)) * 8 + (col & 7);
                    _Float16 h = (_Float16)val;
                    qA[offL] = h;
                    qA[offH] = h;          // duplicate hi into K-slots 16..27
                    qB[offL] = (_Float16)(val - (float)h);
                    qB[offH] = (_Float16)0.0f;   // zero K-slots 16..27
                }
            } else {
                const int d = dst[row];
                if (d >= 0) {
                    const int bb = row >> 11;
                    if (w == 1) {          // K -> packed hi|lo A-frag (compacted)
                        size_t fb = ((size_t)(bb * 128 + (d >> 4))) * 64;
                        size_t offH = (fb + (col >> 3) * 16 + (d & 15)) * 8 + (col & 7);
                        size_t offL = (fb + (2 + (col >> 3)) * 16 + (d & 15)) * 8 + (col & 7);
                        if (col < 12) {
                            _Float16 h = (_Float16)val;
                            kfp[offH] = h;
                            kfp[offL] = (_Float16)(val - (float)h);
                        } else {           // col 12..15: zero pads at slots 12..15 / 28..31
                            kfp[offH] = (_Float16)0.0f;
                            kfp[offL] = (_Float16)0.0f;
                        }
                    } else {               // V^T -> A-frag layout (fp16), + ones row
                        if (col < 12) {
                            size_t off = (((size_t)(bb * 128 + (d >> 4))) * 64
                                          + ((d & 15) >> 2) * 16 + col) * 4 + (d & 3);
                            vtf[off] = (_Float16)val;
                        } else if (col == 12) {   // l-accumulator ones row
                            size_t off = (((size_t)(bb * 128 + (d >> 4))) * 64
                                          + ((d & 15) >> 2) * 16 + 12) * 4 + (d & 3);
                            vtf[off] = (_Float16)1.0f;
                        }
                    }
                }
            }
        }
    }
}

// ---------------- Kernel 2: MFMA flash attention ---------------------------
// grid=1024 (ONE 16-row q-group per block), block=256 (4 waves). Each wave
// now batches TWO key-tiles (t, t+4) per iteration, stride 8: the two score
// MFMAs + fmax trees are independent (2x ILP), and the butterfly max /
// __all / rescale are shared via the joint max pm = max(pm_t, pm_t2)
// (valid online-softmax batching; both tiles' P use the same reference max).
// Cross-lane max via permlane-swap intrinsics. Last-tile invalid keys
// zeroed in-register. XCD swizzle: batch = blockIdx&7.
__global__ __launch_bounds__(256)
void attn(const _Float16* __restrict__ qAf, const _Float16* __restrict__ qBf,
          const _Float16* __restrict__ kfp, const _Float16* __restrict__ vtf,
          const int* __restrict__ nvalid, float* __restrict__ out)
{
    __shared__ float cm[256];
    __shared__ __align__(16) floatx4 co[256];
    const int tid  = threadIdx.x;
    const int lane = tid & 63;
    const int w    = tid >> 6;
    const int bb   = blockIdx.x & 7;       // XCD-pinned batch
    const int gl   = blockIdx.x >> 3;      // 0..127 within batch
    const int g0   = bb * 128 + gl;        // q-group
    const int m15  = lane & 15;

    const half8 qA0 = *(const half8*)(qAf + ((size_t)g0 * 64 + lane) * 8);
    const half8 qB0 = *(const half8*)(qBf + ((size_t)g0 * 64 + lane) * 8);

    const half8* KP = (const half8*)kfp + (size_t)bb * 128 * 64;
    const half4_t* VT = (const half4_t*)vtf + (size_t)bb * 128 * 64;

    const int nv = nvalid[bb];
    const int nt = (nv + 15) >> 4;         // 16-key tiles (<=128)

    float m0 = -INFINITY;
    floatx4 o0 = {0.f, 0.f, 0.f, 0.f};

    int t = w;
    half8 kp, kp2;
    half4_t va, va2;
    if (t < nt)     { kp  = KP[t * 64 + lane];       va  = VT[t * 64 + lane]; }
    if (t + 4 < nt) { kp2 = KP[(t + 4) * 64 + lane]; va2 = VT[(t + 4) * 64 + lane]; }
    for (; t < nt; t += 8) {
        const int t2 = t + 4;
        const bool has2 = (t2 < nt);       // wave-uniform
        half8 nkp, nkp2; half4_t nva, nva2;
        if (t + 8 < nt)  { nkp  = KP[(t + 8) * 64 + lane];  nva  = VT[(t + 8) * 64 + lane]; }
        if (t + 12 < nt) { nkp2 = KP[(t + 12) * 64 + lane]; nva2 = VT[(t + 12) * 64 + lane]; }
        // mask invalid keys of the last tile (only tile nt-1 is partial)
        if (t == nt - 1) {
            const int kb = t * 16;
            if (kb + m15 >= nv) {
                #pragma unroll
                for (int j = 0; j < 8; ++j) kp[j] = (_Float16)0.0f;
            }
            const int kv = kb + (lane >> 4) * 4;
            #pragma unroll
            for (int j = 0; j < 4; ++j)
                if (kv + j >= nv) va[j] = (_Float16)0.0f;
        }
        if (has2 && t2 == nt - 1) {
            const int kb = t2 * 16;
            if (kb + m15 >= nv) {
                #pragma unroll
                for (int j = 0; j < 8; ++j) kp2[j] = (_Float16)0.0f;
            }
            const int kv = kb + (lane >> 4) * 4;
            #pragma unroll
            for (int j = 0; j < 4; ++j)
                if (kv + j >= nv) va2[j] = (_Float16)0.0f;
        }
        const floatx4 z = {0.f, 0.f, 0.f, 0.f};
        floatx4 s0a = MFMA32F16(kp, qA0, z);   // kh*qh + kl*qh  (tile t)
        floatx4 s0b = MFMA32F16(kp, qB0, z);   // kh*ql
        floatx4 s1 = z;
        if (has2) {
            floatx4 s1a = MFMA32F16(kp2, qA0, z);
            floatx4 s1b = MFMA32F16(kp2, qB0, z);
            s1 = s1a + s1b;
        }
        floatx4 s0 = s0a + s0b;
        float pm = fmaxf(fmaxf(s0.x, s0.y), fmaxf(s0.z, s0.w));
        if (has2) {
            float pm1 = fmaxf(fmaxf(s1.x, s1.y), fmaxf(s1.z, s1.w));
            pm = fmaxf(pm, pm1);
        }
        pm = xmax16(pm);
        pm = xmax32(pm);
        float mref;
        if (__all(pm <= m0)) {                 // defer: reference max unchanged
            mref = m0;
        } else {
            float mnew = fmaxf(m0, pm);
            float corr = EXP2F(m0 - mnew);
            o0.x *= corr; o0.y *= corr; o0.z *= corr; o0.w *= corr;
            m0 = mnew; mref = mnew;
        }
        half4_t pb;
        pb[0] = (_Float16)EXP2F(s0.x - mref);
        pb[1] = (_Float16)EXP2F(s0.y - mref);
        pb[2] = (_Float16)EXP2F(s0.z - mref);
        pb[3] = (_Float16)EXP2F(s0.w - mref);
        o0 = MFMA16F16(va, pb, o0);
        if (has2) {
            half4_t pb2;
            pb2[0] = (_Float16)EXP2F(s1.x - mref);
            pb2[1] = (_Float16)EXP2F(s1.y - mref);
            pb2[2] = (_Float16)EXP2F(s1.z - mref);
            pb2[3] = (_Float16)EXP2F(s1.w - mref);
            o0 = MFMA16F16(va2, pb2, o0);
        }
        kp = nkp; va = nva; kp2 = nkp2; va2 = nva2;
    }

    // ---- 4-way combine ----
    cm[w * 64 + lane] = m0;
    co[w * 64 + lane] = o0;
    __syncthreads();
    if (w == 0) {
        float gm = -INFINITY;
        #pragma unroll
        for (int w2 = 0; w2 < 4; ++w2) gm = fmaxf(gm, cm[w2 * 64 + lane]);
        floatx4 O = {0.f, 0.f, 0.f, 0.f};
        #pragma unroll
        for (int w2 = 0; w2 < 4; ++w2) {
            float f = EXP2F(cm[w2 * 64 + lane] - gm);
            floatx4 ow = co[w2 * 64 + lane];
            O.x += ow.x * f; O.y += ow.y * f; O.z += ow.z * f; O.w += ow.w * f;
        }
        float L = bperm(O.x, (48 + m15) << 2);   // l at C row 12
        float inv = 1.0f / L;
        if ((lane >> 4) < 3) {
            float4 ov = make_float4(O.x * inv, O.y * inv, O.z * inv, O.w * inv);
            *(float4*)(out + ((size_t)g0 * 16 + m15) * 12 + (lane >> 4) * 4) = ov;
        }
    }
}

extern "C" void kernel_launch(void* const* d_in, const int* in_sizes, int n_in,
                              void* d_out, int out_size, void* d_ws, size_t ws_size,
                              hipStream_t stream) {
    const float* x    = (const float*)d_in[0];
    const int*   mask = (const int*)  d_in[1];
    const float* Wk   = (const float*)d_in[2];   // key_weight
    const float* Wq   = (const float*)d_in[3];   // query_weight
    const float* Wv   = (const float*)d_in[4];   // value_weight
    float* out = (float*)d_out;

    char* base = (char*)d_ws;
    _Float16* qA  = (_Float16*)(base);                    // 1 MB (poison ok)
    _Float16* qB  = (_Float16*)(base + (1u << 20));       // 1 MB (pads written by qkv)
    _Float16* kfp = (_Float16*)(base + (2u << 20));       // 1 MB (pads written by qkv)
    _Float16* vtf = (_Float16*)(base + (3u << 20));       // 0.5 MB (poison rows unread)
    _Float16* wfh = (_Float16*)(base + 3670016);          // 73728 B
    _Float16* wfl = (_Float16*)(base + 3670016 + 73728);  // 73728 B
    int* dst      = (int*)(base + 3817472);               // 64 KB
    int* nvalid   = (int*)(base + 3817472 + 65536);       // 32 B

    prep<<<26, 256, 0, stream>>>(Wq, Wk, Wv, mask, wfh, wfl, dst, nvalid);
    qkv_mfma<<<1024, 256, 0, stream>>>(x, wfh, wfl, dst, qA, qB, kfp, vtf);
    attn<<<1024, 256, 0, stream>>>(qA, qB, kfp, vtf, nvalid, out);
}